// Round 1
// baseline (465.129 us; speedup 1.0000x reference)
//
#include <hip/hip_runtime.h>
#include <hip/hip_bf16.h>

#define DIN 256
#define DH  1024
#define DF  512

typedef __attribute__((ext_vector_type(8))) short bf16x8;
typedef __attribute__((ext_vector_type(4))) float f32x4;

__device__ __forceinline__ unsigned short f2b(float f) {
    union { float f; unsigned u; } v; v.f = f;
    unsigned r = v.u + 0x7FFFu + ((v.u >> 16) & 1u);
    return (unsigned short)(r >> 16);
}

__device__ __forceinline__ void gll16(const void* g, void* l) {
    __builtin_amdgcn_global_load_lds(
        (const __attribute__((address_space(1))) void*)g,
        (__attribute__((address_space(3))) void*)l, 16, 0, 0);
}

// dst[n][k] = (bf16) src[k][n] ; src is K x N row-major fp32
__global__ __launch_bounds__(256) void transpose_to_bf16(
        const float* __restrict__ src, unsigned short* __restrict__ dst,
        int K, int N) {
    __shared__ float tile[64][65];
    int k0 = blockIdx.x * 64, n0 = blockIdx.y * 64;
    int t = threadIdx.x;
    for (int i = 0; i < 16; ++i) {
        int idx = t + i * 256;
        int kk = idx >> 6, nn = idx & 63;
        tile[kk][nn] = src[(size_t)(k0 + kk) * N + (n0 + nn)];
    }
    __syncthreads();
    for (int i = 0; i < 16; ++i) {
        int idx = t + i * 256;
        int nn = idx >> 6, kk = idx & 63;
        dst[(size_t)(n0 + nn) * K + (k0 + kk)] = f2b(tile[kk][nn]);
    }
}

// LDS layout (dynamic, bytes):
//   ldsX  : [128][256] bf16  = 65536   @ 0        (persistent, swizzled)
//   ldsW1 : [64 ][256] bf16  = 32768   @ 65536    (W1^T chunk: rows = hidden col)
//   ldsH  : [128][64 ] bf16  = 16384   @ 98304
//   ldsW2 : [256][64 ] bf16  = 32768   @ 114688   (W2^T half-chunk)
//   ldsTag: int[128]         = 512     @ 147456
// total 147968
__global__ __launch_bounds__(512) void fused_mlp(
    const float* __restrict__ obs,
    const unsigned short* __restrict__ wts,
    const float* __restrict__ b1_0, const float* __restrict__ b2_0,
    const float* __restrict__ b1_1, const float* __restrict__ b2_1,
    const float* __restrict__ b1_2, const float* __restrict__ b2_2,
    float* __restrict__ out)
{
    extern __shared__ char lds[];
    char* ldsX  = lds;
    char* ldsW1 = lds + 65536;
    char* ldsH  = lds + 98304;
    char* ldsW2 = lds + 114688;
    int*  ldsTag = (int*)(lds + 147456);

    const int bid = blockIdx.x;
    const int branch = bid >> 9;          // 0=b,1=c,2=p
    const int R0 = (bid & 511) * 128;
    const int t = threadIdx.x;
    const int lane = t & 63;
    const int w = t >> 6;                 // wave 0..7
    const int l15 = lane & 15;
    const int g = lane >> 4;              // 0..3

    const float* b1 = branch == 0 ? b1_0 : (branch == 1 ? b1_1 : b1_2);
    const float* b2 = branch == 0 ? b2_0 : (branch == 1 ? b2_1 : b2_2);
    const unsigned short* w1t = wts + (size_t)branch * (DH * DIN);
    const unsigned short* w2t = wts + (size_t)3 * DH * DIN + (size_t)branch * (DF * DH);

    // ---- prologue: stage X (fp32 -> bf16, swizzled), compute row tags
    for (int i = 0; i < 16; ++i) {
        int idx = t + i * 512;            // float4 index; 8192 total
        int r  = idx >> 6;
        int c4 = idx & 63;
        f32x4 v = *(const f32x4*)(obs + (size_t)(R0 + r) * DIN + c4 * 4);
        ushort4 p;
        p.x = f2b(v.x); p.y = f2b(v.y); p.z = f2b(v.z); p.w = f2b(v.w);
        *(ushort4*)(ldsX + r * 512 + ((c4 * 8) ^ ((r & 7) << 4))) = p;
    }
    if (t < 128) {
        float c2 = obs[(size_t)(R0 + t) * DIN + 2];
        float c3 = obs[(size_t)(R0 + t) * DIN + 3];
        ldsTag[t] = (c2 == 1.0f && c3 == 0.0f) ? 1 : 0;
    }
    __syncthreads();

    // GEMM1 wave mapping: rows (w&3)*32 (2x16), cols (w>>2)*32 (2x16) of the 64-wide H chunk
    // GEMM2 wave mapping: rows (w>>2)*64 (4x16), cols (w&3)*64 (4x16) within each 256-col half
    const int wr2 = w >> 2;
    const int wc2 = w & 3;

    f32x4 acc[4][8];
    #pragma unroll
    for (int a = 0; a < 4; ++a)
        #pragma unroll
        for (int b = 0; b < 8; ++b)
            #pragma unroll
            for (int e = 0; e < 4; ++e) acc[a][b][e] = 0.0f;

    for (int hcI = 0; hcI < 16; ++hcI) {
        // ---- stage W1^T chunk (rows hcI*64..+64, 512B each)
        #pragma unroll
        for (int i = 0; i < 4; ++i) {
            int slot = t + i * 512;
            int nl = slot >> 5;
            int boff = (slot & 31) << 4;
            const char* src = (const char*)(w1t + (size_t)(hcI * 64 + nl) * DIN)
                              + (boff ^ ((nl & 7) << 4));
            gll16(src, ldsW1 + slot * 16);
        }
        // ---- stage W2^T half 0 (rows 0..255, k-slice hcI*64..+64)
        #pragma unroll
        for (int i = 0; i < 4; ++i) {
            int slot = t + i * 512;
            int nl = slot >> 3;
            int boff = (slot & 7) << 4;
            const char* src = (const char*)(w2t + (size_t)nl * DH + hcI * 64)
                              + (boff ^ ((nl & 7) << 4));
            gll16(src, ldsW2 + slot * 16);
        }
        __syncthreads();   // compiler drains vmcnt before barrier

        // ---- GEMM1: H[128][64] chunk, K = 256
        f32x4 accH[2][2];
        #pragma unroll
        for (int a = 0; a < 2; ++a)
            #pragma unroll
            for (int b = 0; b < 2; ++b)
                #pragma unroll
                for (int e = 0; e < 4; ++e) accH[a][b][e] = 0.0f;

        const int ar0 = (w & 3) * 32 + l15;
        const int ar1 = ar0 + 16;
        const int bn0 = (w >> 2) * 32 + l15;
        const int bn1 = bn0 + 16;
        #pragma unroll
        for (int kk = 0; kk < 8; ++kk) {
            int kb = kk * 64 + g * 16;
            bf16x8 a0 = *(const bf16x8*)(ldsX  + ar0 * 512 + (kb ^ ((ar0 & 7) << 4)));
            bf16x8 a1 = *(const bf16x8*)(ldsX  + ar1 * 512 + (kb ^ ((ar1 & 7) << 4)));
            bf16x8 b0 = *(const bf16x8*)(ldsW1 + bn0 * 512 + (kb ^ ((bn0 & 7) << 4)));
            bf16x8 b1f = *(const bf16x8*)(ldsW1 + bn1 * 512 + (kb ^ ((bn1 & 7) << 4)));
            accH[0][0] = __builtin_amdgcn_mfma_f32_16x16x32_bf16(a0, b0,  accH[0][0], 0, 0, 0);
            accH[0][1] = __builtin_amdgcn_mfma_f32_16x16x32_bf16(a0, b1f, accH[0][1], 0, 0, 0);
            accH[1][0] = __builtin_amdgcn_mfma_f32_16x16x32_bf16(a1, b0,  accH[1][0], 0, 0, 0);
            accH[1][1] = __builtin_amdgcn_mfma_f32_16x16x32_bf16(a1, b1f, accH[1][1], 0, 0, 0);
        }
        // bias + relu + bf16 -> ldsH  (C/D: col = l15, row = g*4 + r)
        {
            float b1v0 = b1[hcI * 64 + (w >> 2) * 32 + l15];
            float b1v1 = b1[hcI * 64 + (w >> 2) * 32 + 16 + l15];
            #pragma unroll
            for (int rt = 0; rt < 2; ++rt)
                #pragma unroll
                for (int ct = 0; ct < 2; ++ct) {
                    float bv = ct ? b1v1 : b1v0;
                    int col = (w >> 2) * 32 + ct * 16 + l15;
                    #pragma unroll
                    for (int r = 0; r < 4; ++r) {
                        int hrow = (w & 3) * 32 + rt * 16 + g * 4 + r;
                        float vv = accH[rt][ct][r] + bv;
                        vv = fmaxf(vv, 0.0f);
                        *(unsigned short*)(ldsH + hrow * 128 + ((col * 2) ^ ((hrow & 7) << 4))) = f2b(vv);
                    }
                }
        }
        __syncthreads();   // H visible to all waves

        // cache H A-frags for this chunk (reused by both halves)
        bf16x8 hA[4][2];
        #pragma unroll
        for (int rt = 0; rt < 4; ++rt)
            #pragma unroll
            for (int kk = 0; kk < 2; ++kk) {
                int row = wr2 * 64 + rt * 16 + l15;
                int kb = kk * 64 + g * 16;
                hA[rt][kk] = *(const bf16x8*)(ldsH + row * 128 + (kb ^ ((row & 7) << 4)));
            }

        // ---- GEMM2 half 0 (out cols 0..255)
        #pragma unroll
        for (int kk = 0; kk < 2; ++kk)
            #pragma unroll
            for (int ct = 0; ct < 4; ++ct) {
                int bn = wc2 * 64 + ct * 16 + l15;
                int kb = kk * 64 + g * 16;
                bf16x8 bf = *(const bf16x8*)(ldsW2 + bn * 128 + (kb ^ ((bn & 7) << 4)));
                #pragma unroll
                for (int rt = 0; rt < 4; ++rt)
                    acc[rt][ct] = __builtin_amdgcn_mfma_f32_16x16x32_bf16(hA[rt][kk], bf, acc[rt][ct], 0, 0, 0);
            }
        __syncthreads();   // half-0 B reads done

        // ---- stage W2^T half 1 (rows 256..511)
        #pragma unroll
        for (int i = 0; i < 4; ++i) {
            int slot = t + i * 512;
            int nl = slot >> 3;
            int boff = (slot & 7) << 4;
            const char* src = (const char*)(w2t + (size_t)(256 + nl) * DH + hcI * 64)
                              + (boff ^ ((nl & 7) << 4));
            gll16(src, ldsW2 + slot * 16);
        }
        __syncthreads();   // drain

        // ---- GEMM2 half 1 (out cols 256..511)
        #pragma unroll
        for (int kk = 0; kk < 2; ++kk)
            #pragma unroll
            for (int ct = 0; ct < 4; ++ct) {
                int bn = wc2 * 64 + ct * 16 + l15;
                int kb = kk * 64 + g * 16;
                bf16x8 bf = *(const bf16x8*)(ldsW2 + bn * 128 + (kb ^ ((bn & 7) << 4)));
                #pragma unroll
                for (int rt = 0; rt < 4; ++rt)
                    acc[rt][4 + ct] = __builtin_amdgcn_mfma_f32_16x16x32_bf16(hA[rt][kk], bf, acc[rt][4 + ct], 0, 0, 0);
            }
        __syncthreads();   // protect all LDS buffers for next chunk
    }

    // ---- epilogue: bias2 + per-row select + store fp32
    int colg[8]; float b2v[8];
    #pragma unroll
    for (int cg = 0; cg < 8; ++cg) {
        colg[cg] = (cg >> 2) * 256 + wc2 * 64 + (cg & 3) * 16 + l15;
        b2v[cg] = b2[colg[cg]];
    }
    const int colbase = (branch == 2) ? DF : 0;
    #pragma unroll
    for (int rt = 0; rt < 4; ++rt)
        #pragma unroll
        for (int r = 0; r < 4; ++r) {
            int row = wr2 * 64 + rt * 16 + g * 4 + r;
            bool sel = true;
            if (branch != 2) {
                int tg = ldsTag[row];
                sel = (branch == 0) ? (tg != 0) : (tg == 0);
            }
            if (sel) {
                float* op = out + (size_t)(R0 + row) * (2 * DF) + colbase;
                #pragma unroll
                for (int cg = 0; cg < 8; ++cg)
                    op[colg[cg]] = acc[rt][cg][r] + b2v[cg];
            }
        }
}

extern "C" void kernel_launch(void* const* d_in, const int* in_sizes, int n_in,
                              void* d_out, int out_size, void* d_ws, size_t ws_size,
                              hipStream_t stream) {
    const float* obs = (const float*)d_in[0];
    const float* W1[3] = {(const float*)d_in[1], (const float*)d_in[5], (const float*)d_in[9]};
    const float* b1[3] = {(const float*)d_in[2], (const float*)d_in[6], (const float*)d_in[10]};
    const float* W2[3] = {(const float*)d_in[3], (const float*)d_in[7], (const float*)d_in[11]};
    const float* b2[3] = {(const float*)d_in[4], (const float*)d_in[8], (const float*)d_in[12]};
    unsigned short* wts = (unsigned short*)d_ws;

    // prep: transpose+convert weights to bf16 [fan_out][fan_in] in workspace (4.72 MB)
    for (int br = 0; br < 3; ++br) {
        transpose_to_bf16<<<dim3(DIN / 64, DH / 64), 256, 0, stream>>>(
            W1[br], wts + (size_t)br * DH * DIN, DIN, DH);
        transpose_to_bf16<<<dim3(DH / 64, DF / 64), 256, 0, stream>>>(
            W2[br], wts + (size_t)3 * DH * DIN + (size_t)br * DF * DH, DH, DF);
    }

    hipFuncSetAttribute((const void*)fused_mlp,
                        hipFuncAttributeMaxDynamicSharedMemorySize, 147968);
    fused_mlp<<<1536, 512, 147968, stream>>>(obs, wts,
        b1[0], b2[0], b1[1], b2[1], b1[2], b2[2], (float*)d_out);
}

// Round 2
// 420.811 us; speedup vs baseline: 1.1053x; 1.1053x over previous
//
#include <hip/hip_runtime.h>
#include <hip/hip_bf16.h>

#define DIN 256
#define DH  1024
#define DF  512
#define NROWS 65536

// workspace layout (bytes)
#define WS_WTS   0
#define WS_PB    4718592
#define WS_PC    4980736
#define WS_CNT   5242880
#define WS_OFFS  5243904

typedef __attribute__((ext_vector_type(8))) short bf16x8;
typedef __attribute__((ext_vector_type(4))) float f32x4;

__device__ __forceinline__ unsigned short f2b(float f) {
    union { float f; unsigned u; } v; v.f = f;
    unsigned r = v.u + 0x7FFFu + ((v.u >> 16) & 1u);
    return (unsigned short)(r >> 16);
}

__device__ __forceinline__ void gll16(const void* g, void* l) {
    __builtin_amdgcn_global_load_lds(
        (const __attribute__((address_space(1))) void*)g,
        (__attribute__((address_space(3))) void*)l, 16, 0, 0);
}

// dst[n][k] = (bf16) src[k][n] ; src is K x N row-major fp32
__global__ __launch_bounds__(256) void transpose_to_bf16(
        const float* __restrict__ src, unsigned short* __restrict__ dst,
        int K, int N) {
    __shared__ float tile[64][65];
    int k0 = blockIdx.x * 64, n0 = blockIdx.y * 64;
    int t = threadIdx.x;
    for (int i = 0; i < 16; ++i) {
        int idx = t + i * 256;
        int kk = idx >> 6, nn = idx & 63;
        tile[kk][nn] = src[(size_t)(k0 + kk) * N + (n0 + nn)];
    }
    __syncthreads();
    for (int i = 0; i < 16; ++i) {
        int idx = t + i * 256;
        int nn = idx >> 6, kk = idx & 63;
        dst[(size_t)(n0 + nn) * K + (k0 + kk)] = f2b(tile[kk][nn]);
    }
}

__device__ __forceinline__ int row_tag(const float* obs, int row) {
    float c2 = obs[(size_t)row * DIN + 2];
    float c3 = obs[(size_t)row * DIN + 3];
    return (c2 == 1.0f && c3 == 0.0f) ? 1 : 0;
}

__global__ __launch_bounds__(256) void tag_count(const float* __restrict__ obs,
                                                 int* __restrict__ cnt) {
    int t = threadIdx.x;
    int tag = row_tag(obs, blockIdx.x * 256 + t);
    unsigned long long m = __ballot(tag);
    __shared__ int wc[4];
    if ((t & 63) == 0) wc[t >> 6] = __popcll(m);
    __syncthreads();
    if (t == 0) cnt[blockIdx.x] = wc[0] + wc[1] + wc[2] + wc[3];
}

__global__ __launch_bounds__(256) void scan256(const int* __restrict__ cnt,
                                               int* __restrict__ offs) {
    __shared__ int s[256];
    int t = threadIdx.x;
    s[t] = cnt[t];
    __syncthreads();
    for (int d = 1; d < 256; d <<= 1) {
        int v = (t >= d) ? s[t - d] : 0;
        __syncthreads();
        s[t] += v;
        __syncthreads();
    }
    offs[t] = s[t] - cnt[t];
    if (t == 255) offs[256] = s[255];
}

__global__ __launch_bounds__(256) void fill_perm(const float* __restrict__ obs,
                                                 const int* __restrict__ offs,
                                                 int* __restrict__ pb,
                                                 int* __restrict__ pc) {
    int t = threadIdx.x, bid = blockIdx.x;
    int row = bid * 256 + t;
    int tag = row_tag(obs, row);
    unsigned long long m = __ballot(tag);
    __shared__ int wc[4];
    int lane = t & 63, wv = t >> 6;
    if (lane == 0) wc[wv] = __popcll(m);
    __syncthreads();
    int woff = 0;
    for (int i = 0; i < 4; ++i) if (i < wv) woff += wc[i];
    int lb = woff + __popcll(m & ((1ull << lane) - 1ull));
    int base_b = offs[bid];
    if (tag) pb[base_b + lb] = row;
    else     pc[bid * 256 - base_b + (t - lb)] = row;
}

// LDS (dynamic, 69632 B total => 2 blocks/CU):
//   ldsX  : [64][256] bf16 = 32768 @ 0      swz ((r&7)<<4)
//   ldsW1 : [32][256] bf16 = 16384 @ 32768  swz ((r&7)<<4)   (also W2 half-1: [256][32], swz ((r&3)<<4))
//   ldsH  : [64][32]  bf16 =  4096 @ 49152  swz ((r&3)<<4)
//   ldsW2 : [256][32] bf16 = 16384 @ 53248  swz ((r&3)<<4)
__global__ __launch_bounds__(512, 4) void fused_mlp(
    const float* __restrict__ obs,
    const unsigned short* __restrict__ wts,
    const int* __restrict__ perm_b, const int* __restrict__ perm_c,
    const int* __restrict__ offs,
    const float* __restrict__ b1_0, const float* __restrict__ b2_0,
    const float* __restrict__ b1_1, const float* __restrict__ b2_1,
    const float* __restrict__ b1_2, const float* __restrict__ b2_2,
    float* __restrict__ out)
{
    extern __shared__ char lds[];
    char* ldsX  = lds;
    char* ldsW1 = lds + 32768;
    char* ldsH  = lds + 49152;
    char* ldsW2 = lds + 53248;

    const int bid = blockIdx.x;
    int branch, base, cnt;
    const int* perm;
    if (bid < 1024) {
        branch = 2; base = bid * 64; cnt = NROWS; perm = nullptr;
    } else {
        int eb = bid - 1024;
        int nb = offs[256];
        int nbb = (nb + 63) >> 6;
        int nc = NROWS - nb;
        int ncb = (nc + 63) >> 6;
        if (eb < nbb)            { branch = 0; base = eb * 64;         cnt = nb; perm = perm_b; }
        else if (eb < nbb + ncb) { branch = 1; base = (eb - nbb) * 64; cnt = nc; perm = perm_c; }
        else return;
    }

    const float* b1 = branch == 0 ? b1_0 : (branch == 1 ? b1_1 : b1_2);
    const float* b2 = branch == 0 ? b2_0 : (branch == 1 ? b2_1 : b2_2);
    const unsigned short* w1t = wts + (size_t)branch * (DH * DIN);
    const unsigned short* w2t = wts + (size_t)3 * DH * DIN + (size_t)branch * (DF * DH);

    const int t = threadIdx.x;
    const int lane = t & 63;
    const int w = t >> 6;
    const int l15 = lane & 15;
    const int g = lane >> 4;

    // ---- prologue: stage X (gathered rows, fp32->bf16, swizzled)
    #pragma unroll
    for (int i = 0; i < 8; ++i) {
        int idx = t + i * 512;        // float4 slot: 4096 total = 64 rows x 64
        int r = idx >> 6, c4 = idx & 63;
        int gr = base + r;
        int grow = gr < cnt ? gr : cnt - 1;
        if (perm) grow = perm[grow];
        f32x4 v = *(const f32x4*)(obs + (size_t)grow * DIN + c4 * 4);
        ushort4 p4;
        p4.x = f2b(v.x); p4.y = f2b(v.y); p4.z = f2b(v.z); p4.w = f2b(v.w);
        *(ushort4*)(ldsX + r * 512 + ((c4 * 8) ^ ((r & 7) << 4))) = p4;
    }
    __syncthreads();

    const int rg = w & 3, cg = w >> 2;   // GEMM1: 4 row-groups x 2 col-groups
    const int wr = w >> 2, wc = w & 3;   // GEMM2: 2 row-groups x 4 col-groups

    f32x4 acc[2][8];
    #pragma unroll
    for (int a = 0; a < 2; ++a)
        #pragma unroll
        for (int b = 0; b < 8; ++b)
            #pragma unroll
            for (int e = 0; e < 4; ++e) acc[a][b][e] = 0.0f;

    const int ar = rg * 16 + l15;        // X row
    const int br = cg * 16 + l15;        // W1 chunk row (= hidden col)
    const int xsw = (ar & 7) << 4;
    const int bsw = (br & 7) << 4;

    for (int hc = 0; hc < 32; ++hc) {
        // ---- stage W1 chunk [32][256] (16KB: 2 gll/thread)
        #pragma unroll
        for (int i = 0; i < 2; ++i) {
            int slot = t + i * 512;
            int nl = slot >> 5, boff = (slot & 31) << 4;
            const char* src = (const char*)(w1t + (size_t)(hc * 32 + nl) * DIN)
                              + (boff ^ ((nl & 7) << 4));
            gll16(src, ldsW1 + slot * 16);
        }
        // ---- stage W2 half0 [256][32] (16KB)
        #pragma unroll
        for (int i = 0; i < 2; ++i) {
            int slot = t + i * 512;
            int nl = slot >> 2, boff = (slot & 3) << 4;
            const char* src = (const char*)(w2t + (size_t)nl * DH + hc * 32)
                              + (boff ^ ((nl & 3) << 4));
            gll16(src, ldsW2 + slot * 16);
        }
        __syncthreads();

        // ---- GEMM1: H chunk [64][32], K=256
        f32x4 accH;
        accH[0] = 0.0f; accH[1] = 0.0f; accH[2] = 0.0f; accH[3] = 0.0f;
        #pragma unroll
        for (int kk = 0; kk < 8; ++kk) {
            int kb = kk * 64 + g * 16;
            bf16x8 a  = *(const bf16x8*)(ldsX  + ar * 512 + (kb ^ xsw));
            bf16x8 bf = *(const bf16x8*)(ldsW1 + br * 512 + (kb ^ bsw));
            accH = __builtin_amdgcn_mfma_f32_16x16x32_bf16(a, bf, accH, 0, 0, 0);
        }
        // bias + relu -> ldsH (C/D: col=l15, row=g*4+r)
        {
            float b1v = b1[hc * 32 + cg * 16 + l15];
            int hcol2 = (cg * 16 + l15) * 2;
            #pragma unroll
            for (int r = 0; r < 4; ++r) {
                int hrow = rg * 16 + g * 4 + r;
                float vv = fmaxf(accH[r] + b1v, 0.0f);
                *(unsigned short*)(ldsH + hrow * 64 + (hcol2 ^ ((hrow & 3) << 4))) = f2b(vv);
            }
        }
        __syncthreads();

        // ---- stage W2 half1 into ldsW1 (free now); drain hides under GEMM2 h0
        #pragma unroll
        for (int i = 0; i < 2; ++i) {
            int slot = t + i * 512;
            int nl = slot >> 2, boff = (slot & 3) << 4;
            const char* src = (const char*)(w2t + (size_t)(256 + nl) * DH + hc * 32)
                              + (boff ^ ((nl & 3) << 4));
            gll16(src, ldsW1 + slot * 16);
        }

        // A-frags for GEMM2 (reused by both halves)
        bf16x8 hA[2];
        #pragma unroll
        for (int rt = 0; rt < 2; ++rt) {
            int hr = wr * 32 + rt * 16 + l15;
            hA[rt] = *(const bf16x8*)(ldsH + hr * 64 + ((g * 16) ^ ((hr & 3) << 4)));
        }

        // ---- GEMM2 half0 (out cols 0..255) from ldsW2
        #pragma unroll
        for (int ct = 0; ct < 4; ++ct) {
            int bc = wc * 64 + ct * 16 + l15;
            bf16x8 bf = *(const bf16x8*)(ldsW2 + bc * 64 + ((g * 16) ^ ((bc & 3) << 4)));
            #pragma unroll
            for (int rt = 0; rt < 2; ++rt)
                acc[rt][ct] = __builtin_amdgcn_mfma_f32_16x16x32_bf16(hA[rt], bf, acc[rt][ct], 0, 0, 0);
        }
        __syncthreads();   // drains half1 staging

        // ---- GEMM2 half1 (out cols 256..511) from ldsW1
        #pragma unroll
        for (int ct = 0; ct < 4; ++ct) {
            int bc = wc * 64 + ct * 16 + l15;
            bf16x8 bf = *(const bf16x8*)(ldsW1 + bc * 64 + ((g * 16) ^ ((bc & 3) << 4)));
            #pragma unroll
            for (int rt = 0; rt < 2; ++rt)
                acc[rt][4 + ct] = __builtin_amdgcn_mfma_f32_16x16x32_bf16(hA[rt], bf, acc[rt][4 + ct], 0, 0, 0);
        }
        __syncthreads();   // protect buffers for next chunk
    }

    // ---- epilogue
    float b2v[8]; int colq[8];
    #pragma unroll
    for (int q = 0; q < 8; ++q) {
        colq[q] = (q >> 2) * 256 + wc * 64 + (q & 3) * 16 + l15;
        b2v[q] = b2[colq[q]];
    }
    const int cb = (branch == 2) ? DF : 0;
    #pragma unroll
    for (int rt = 0; rt < 2; ++rt)
        #pragma unroll
        for (int r = 0; r < 4; ++r) {
            int row = wr * 32 + rt * 16 + g * 4 + r;
            if (base + row < cnt) {
                int prow = perm ? perm[base + row] : base + row;
                float* op = out + (size_t)prow * (2 * DF) + cb;
                #pragma unroll
                for (int q = 0; q < 8; ++q)
                    op[colq[q]] = acc[rt][q][r] + b2v[q];
            }
        }
}

extern "C" void kernel_launch(void* const* d_in, const int* in_sizes, int n_in,
                              void* d_out, int out_size, void* d_ws, size_t ws_size,
                              hipStream_t stream) {
    const float* obs = (const float*)d_in[0];
    const float* W1[3] = {(const float*)d_in[1], (const float*)d_in[5], (const float*)d_in[9]};
    const float* b1[3] = {(const float*)d_in[2], (const float*)d_in[6], (const float*)d_in[10]};
    const float* W2[3] = {(const float*)d_in[3], (const float*)d_in[7], (const float*)d_in[11]};
    const float* b2[3] = {(const float*)d_in[4], (const float*)d_in[8], (const float*)d_in[12]};

    char* ws = (char*)d_ws;
    unsigned short* wts = (unsigned short*)(ws + WS_WTS);
    int* pb   = (int*)(ws + WS_PB);
    int* pc   = (int*)(ws + WS_PC);
    int* cnt  = (int*)(ws + WS_CNT);
    int* offs = (int*)(ws + WS_OFFS);

    for (int br = 0; br < 3; ++br) {
        transpose_to_bf16<<<dim3(DIN / 64, DH / 64), 256, 0, stream>>>(
            W1[br], wts + (size_t)br * DH * DIN, DIN, DH);
        transpose_to_bf16<<<dim3(DH / 64, DF / 64), 256, 0, stream>>>(
            W2[br], wts + (size_t)3 * DH * DIN + (size_t)br * DF * DH, DH, DF);
    }
    tag_count<<<256, 256, 0, stream>>>(obs, cnt);
    scan256<<<1, 256, 0, stream>>>(cnt, offs);
    fill_perm<<<256, 256, 0, stream>>>(obs, offs, pb, pc);

    hipFuncSetAttribute((const void*)fused_mlp,
                        hipFuncAttributeMaxDynamicSharedMemorySize, 69632);
    fused_mlp<<<2050, 512, 69632, stream>>>(obs, wts, pb, pc, offs,
        b1[0], b2[0], b1[1], b2[1], b1[2], b2[2], (float*)d_out);
}